// Round 5
// baseline (178.133 us; speedup 1.0000x reference)
//
#include <hip/hip_runtime.h>

#define NB 4
#define NC 64
#define NH 256
#define NW 256
#define TH 16                    // output rows per block
#define LR 22                    // TH + 6 halo rows
#define LSTR 264                 // LDS row stride in floats (cols -4..259), 1056 B
#define NCHUNK 66                // 16B chunks per LDS row
#define NCHUNKS_TOT (LR * NCHUNK)     // 1452 chunks
#define BUF_BYTES (NCHUNKS_TOT * 16)  // 23232 B -> 6 blocks/CU (LDS-limited)
#define CH_PER 2

// zero-initialized device global: OOB staging taps DMA 16B of zeros from here.
__device__ float g_zero[16] __attribute__((aligned(64)));

static __device__ __forceinline__ void async16(const void* g, void* l) {
    // global -> LDS direct DMA, 16B/lane; LDS dest = wave-uniform base + lane*16
    __builtin_amdgcn_global_load_lds(
        (const __attribute__((address_space(1))) void*)g,
        (__attribute__((address_space(3))) void*)l, 16, 0, 0);
}

// (256,2): VGPR cap 256; body is small (~75 live) so no spill expected.
// Round-2 lesson: (256,4) made the compiler pick 64 VGPR -> 70 MB spill. Avoid.
__global__ __launch_bounds__(256, 2)
void adaptive_gauss7(const float* __restrict__ x,
                     const float* __restrict__ persp,
                     const float* __restrict__ alpha_p,
                     const float* __restrict__ beta_p,
                     const float* __restrict__ gamma_p,
                     float* __restrict__ out)
{
    __shared__ char xs_raw[BUF_BYTES];

    const int tid  = threadIdx.x;
    const int lane = tid & 63;
    const int wv   = tid >> 6;       // 4 waves; wave owns 4 output rows
    const int c0   = blockIdx.x * CH_PER;
    const int h0   = blockIdx.y * TH;
    const int b    = blockIdx.z;
    const int colbase = lane * 4;    // output col base
    const int rbase   = wv * 4;      // first output row in tile

    const float alpha = alpha_p[0];
    const float beta  = beta_p[0];
    const float gamma = gamma_p[0];

    // ---- per-thread staging offsets (6 chunks/thread, reused both channels) ----
    int offs[6];
    #pragma unroll
    for (int it = 0; it < 6; ++it) {
        const int q  = it * 256 + tid;
        const int r  = q / NCHUNK;
        const int cb = (q - r * NCHUNK) * 16 - 16;   // byte col -16 .. 1040
        const int gr = h0 - 3 + r;
        const bool valid = ((unsigned)gr < NH) && ((unsigned)cb < NW * 4);
        offs[it] = valid ? (gr * (NW * 4) + cb) : -1;
    }

    const char* xbase = (const char*)x + (size_t)(b * NC + c0) * NH * NW * 4;

    auto stage = [&](int ci) {
        const char* xc = xbase + (size_t)ci * NH * NW * 4;
        char* lb = xs_raw + wv * 1024;               // wave-uniform base
        #pragma unroll
        for (int it = 0; it < 6; ++it) {
            if (it < 5 || tid < (NCHUNKS_TOT - 5 * 256)) {
                const char* g = (offs[it] >= 0) ? (xc + offs[it]) : (const char*)g_zero;
                async16(g, lb + it * 4096);
            }
        }
    };

    stage(0);   // async; overlaps gw compute below

    // ---- per-pixel g = exp(-1/(2*sigma^2)), once per block (both channels) ----
    float gwv[4][4];
    {
        const float* pp = persp + (size_t)b * NH * NW;
        #pragma unroll
        for (int r = 0; r < 4; ++r) {
            const float4 p4v = *(const float4*)(pp + (size_t)(h0 + rbase + r) * NW + colbase);
            const float pv[4] = {p4v.x, p4v.y, p4v.z, p4v.w};
            #pragma unroll
            for (int k = 0; k < 4; ++k) {
                const float z  = fmaf(beta, pv[k], gamma);
                const float sg = __builtin_amdgcn_rcpf(1.0f + __expf(-z));
                const float sigma = fmaxf(alpha * sg, 1e-4f);
                const float t  = 0.5f * __builtin_amdgcn_rcpf(sigma * sigma);
                gwv[r][k] = __expf(-t);   // g; tap weight = g^(d^2)
            }
        }
    }

    __syncthreads();   // staging 0 drained

    #pragma unroll
    for (int ci = 0; ci < CH_PER; ++ci) {
        const float* xs = (const float*)xs_raw;
        float* outp = out + (size_t)(b * NC + c0 + ci) * NH * NW
                          + (size_t)(h0 + rbase) * NW + colbase;

        #pragma unroll
        for (int orow = 0; orow < 4; ++orow) {
            // window: LDS rows rbase+orow .. +6, cols colbase-4 .. +7
            const float* src = &xs[(rbase + orow) * LSTR + colbase];

            float G[4], P4[4], P9[4], INV2[4];
            #pragma unroll
            for (int k = 0; k < 4; ++k) {
                const float g  = gwv[orow][k];
                const float g2 = g * g;
                G[k]  = g;
                P4[k] = g2 * g2;
                P9[k] = P4[k] * P4[k] * g;
                const float S = fmaf(2.0f, (g + P4[k]) + P9[k], 1.0f);
                const float inv = __builtin_amdgcn_rcpf(S);
                INV2[k] = inv * inv;
            }

            float acc[4] = {0.f, 0.f, 0.f, 0.f};
            #pragma unroll
            for (int j = 0; j < 7; ++j) {
                const float* rp = src + j * LSTR;
                const float4 a0 = *(const float4*)(rp);
                const float4 a1 = *(const float4*)(rp + 4);
                const float4 a2 = *(const float4*)(rp + 8);
                const float w[12] = {a0.x, a0.y, a0.z, a0.w,
                                     a1.x, a1.y, a1.z, a1.w,
                                     a2.x, a2.y, a2.z, a2.w};
                #pragma unroll
                for (int k = 0; k < 4; ++k) {
                    const float rs =
                        fmaf(P9[k], w[k+1] + w[k+7],
                        fmaf(P4[k], w[k+2] + w[k+6],
                        fmaf(G[k],  w[k+3] + w[k+5],
                                    w[k+4])));
                    const float vw = (j == 0 || j == 6) ? P9[k]
                                   : (j == 1 || j == 5) ? P4[k]
                                   : (j == 2 || j == 4) ? G[k] : 1.0f;
                    acc[k] = fmaf(vw, rs, acc[k]);
                }
            }
            *(float4*)(outp + (size_t)orow * NW) =
                make_float4(acc[0] * INV2[0], acc[1] * INV2[1],
                            acc[2] * INV2[2], acc[3] * INV2[3]);
        }

        if (ci + 1 < CH_PER) {
            __syncthreads();      // all reads of buffer done
            stage(ci + 1);        // async restage
            __syncthreads();      // staging drained (vmcnt0 at barrier)
        }
    }
}

extern "C" void kernel_launch(void* const* d_in, const int* in_sizes, int n_in,
                              void* d_out, int out_size, void* d_ws, size_t ws_size,
                              hipStream_t stream) {
    const float* x     = (const float*)d_in[0];
    const float* persp = (const float*)d_in[1];
    const float* alpha = (const float*)d_in[2];
    const float* beta  = (const float*)d_in[3];
    const float* gamma = (const float*)d_in[4];
    float* outp        = (float*)d_out;
    // kernel_size (d_in[5]) fixed at 7 per the reference setup
    dim3 grid(NC / CH_PER, NH / TH, NB);   // 32 x 16 x 4 = 2048 blocks
    adaptive_gauss7<<<grid, dim3(256), 0, stream>>>(x, persp, alpha, beta, gamma, outp);
}

// Round 6
// 143.498 us; speedup vs baseline: 1.2414x; 1.2414x over previous
//
#include <hip/hip_runtime.h>

#define NB 4
#define NC 64
#define NH 256
#define NW 256
#define TH 64                    // output rows per block (wave owns 16)

// 16B-aligned zeros: OOB window chunks load from here (branchless ptr select).
__device__ __attribute__((aligned(64))) float zbuf[16];

// No LDS, no barriers. VGPR budget ~125 (win 84 + pipeline + addr); (256,2)
// caps at 256 so the compiler won't force-spill (round-2 lesson: (256,4)->64 VGPR).
__global__ __launch_bounds__(256, 2)
void adaptive_gauss7(const float* __restrict__ x,
                     const float* __restrict__ persp,
                     const float* __restrict__ alpha_p,
                     const float* __restrict__ beta_p,
                     const float* __restrict__ gamma_p,
                     float* __restrict__ out)
{
    const int tid  = threadIdx.x;
    const int lane = tid & 63;
    const int wv   = tid >> 6;            // 4 waves x 16 rows = 64 rows
    const int c    = blockIdx.x;
    const int h0   = blockIdx.y * TH;
    const int b    = blockIdx.z;
    const int colbase = lane * 4;         // output cols colbase..colbase+3
    const int rg      = h0 + wv * 16;     // first output row of this wave

    const float alpha = alpha_p[0];
    const float beta  = beta_p[0];
    const float gamma = gamma_p[0];

    const float* xc = x     + (size_t)(b * NC + c) * NH * NW;
    const float* pp = persp + (size_t)b * NH * NW;
    float*     outp = out   + (size_t)(b * NC + c) * NH * NW;

    // sliding 7-row x 12-float window (cols colbase-4 .. colbase+7)
    float win[7][12];

    auto loadrow = [&](int slot, int gr) {
        const bool rv = (unsigned)gr < NH;
        const float* p  = xc + (size_t)gr * NW + colbase;
        const float* p0 = (rv && lane != 0)  ? (p - 4) : zbuf;   // cols -4..-1
        const float* p1 =  rv                ?  p      : zbuf;   // cols  0.. 3
        const float* p2 = (rv && lane != 63) ? (p + 4) : zbuf;   // cols  4.. 7
        const float4 a0 = *(const float4*)p0;
        const float4 a1 = *(const float4*)p1;
        const float4 a2 = *(const float4*)p2;
        win[slot][0] = a0.x; win[slot][1] = a0.y; win[slot][2]  = a0.z; win[slot][3]  = a0.w;
        win[slot][4] = a1.x; win[slot][5] = a1.y; win[slot][6]  = a1.z; win[slot][7]  = a1.w;
        win[slot][8] = a2.x; win[slot][9] = a2.y; win[slot][10] = a2.z; win[slot][11] = a2.w;
    };

    // persp pipeline: pvn holds the NEXT output row's perspective
    float4 pvn = *(const float4*)(pp + (size_t)rg * NW + colbase);

    // prime window: input rows rg-3 .. rg+2 -> slots 0..5
    #pragma unroll
    for (int r = 0; r < 6; ++r)
        loadrow(r, rg - 3 + r);

    // main loop: iteration r loads input row rg-3+r, emits output row rg+(r-6)
    #pragma unroll
    for (int r = 6; r < 22; ++r) {
        loadrow(r % 7, rg - 3 + r);

        const float4 pv = pvn;
        if (r < 21)
            pvn = *(const float4*)(pp + (size_t)(rg + r - 5) * NW + colbase);

        const float pva[4] = {pv.x, pv.y, pv.z, pv.w};
        float res[4];
        #pragma unroll
        for (int k = 0; k < 4; ++k) {
            const float z  = fmaf(beta, pva[k], gamma);
            const float sg = __builtin_amdgcn_rcpf(1.0f + __expf(-z));
            const float sigma = fmaxf(alpha * sg, 1e-4f);
            const float t  = 0.5f * __builtin_amdgcn_rcpf(sigma * sigma);
            const float g  = __expf(-t);       // tap weight = g^(d^2)
            const float g2 = g * g;
            const float p4 = g2 * g2;          // g^4
            const float p9 = p4 * p4 * g;      // g^9
            const float S  = fmaf(2.0f, (g + p4) + p9, 1.0f);
            const float inv  = __builtin_amdgcn_rcpf(S);
            const float inv2 = inv * inv;      // 1/S^2

            float rs[7];
            #pragma unroll
            for (int j = 0; j < 7; ++j) {
                const int s = (r - 6 + j) % 7;   // slot of input row (rg+r-9+j)
                rs[j] = fmaf(p9, win[s][k+1] + win[s][k+7],
                        fmaf(p4, win[s][k+2] + win[s][k+6],
                        fmaf(g,  win[s][k+3] + win[s][k+5],
                                 win[s][k+4])));
            }
            const float acc = fmaf(p9, rs[0] + rs[6],
                              fmaf(p4, rs[1] + rs[5],
                              fmaf(g,  rs[2] + rs[4],
                                       rs[3])));
            res[k] = acc * inv2;
        }
        *(float4*)(outp + (size_t)(rg + r - 6) * NW + colbase) =
            make_float4(res[0], res[1], res[2], res[3]);
    }
}

extern "C" void kernel_launch(void* const* d_in, const int* in_sizes, int n_in,
                              void* d_out, int out_size, void* d_ws, size_t ws_size,
                              hipStream_t stream) {
    const float* x     = (const float*)d_in[0];
    const float* persp = (const float*)d_in[1];
    const float* alpha = (const float*)d_in[2];
    const float* beta  = (const float*)d_in[3];
    const float* gamma = (const float*)d_in[4];
    float* outp        = (float*)d_out;
    // kernel_size (d_in[5]) fixed at 7 per the reference setup
    dim3 grid(NC, NH / TH, NB);   // 64 x 4 x 4 = 1024 blocks, ~4/CU
    adaptive_gauss7<<<grid, dim3(256), 0, stream>>>(x, persp, alpha, beta, gamma, outp);
}

// Round 7
// 141.955 us; speedup vs baseline: 1.2549x; 1.0109x over previous
//
#include <hip/hip_runtime.h>

#define NB 4
#define NC 64
#define NH 256
#define NW 256
#define TH 64                    // output rows per block (each wave owns 16)

// 16B-aligned zeros: OOB window chunks load from here (branchless ptr select).
__device__ __attribute__((aligned(64))) float zbuf[16];

// No LDS, no barriers. (256,2) caps VGPR at 256 — round-2 lesson: tighter
// bounds force-spill (70 MB of scratch traffic). Expect ~120-140 VGPR here.
__global__ __launch_bounds__(256, 2)
void adaptive_gauss7(const float* __restrict__ x,
                     const float* __restrict__ persp,
                     const float* __restrict__ alpha_p,
                     const float* __restrict__ beta_p,
                     const float* __restrict__ gamma_p,
                     float* __restrict__ out)
{
    const int tid  = threadIdx.x;
    const int lane = tid & 63;
    const int wv   = tid >> 6;            // 4 waves x 16 rows = 64 rows
    const int c    = blockIdx.x;
    const int h0   = blockIdx.y * TH;
    const int b    = blockIdx.z;
    const int colbase = lane * 4;         // output cols colbase..colbase+3
    const int rg      = h0 + wv * 16;     // first output row of this wave

    const float alpha = alpha_p[0];
    const float beta  = beta_p[0];
    const float gamma = gamma_p[0];

    const float* xc = x     + (size_t)(b * NC + c) * NH * NW;
    const float* pp = persp + (size_t)b * NH * NW;
    float*     outp = out   + (size_t)(b * NC + c) * NH * NW;

    // window holds input rows rg+o-3 .. rg+o+3 when emitting output row rg+o.
    // row gr lives in slot (gr - rg + 3) % 7.
    float win[7][12];

    auto loadrow = [&](float dst[12], int gr) {
        const bool rv = (unsigned)gr < NH;
        const float* p  = xc + (size_t)gr * NW + colbase;
        const float* p0 = (rv && lane != 0)  ? (p - 4) : zbuf;   // cols -4..-1
        const float* p1 =  rv                ?  p      : zbuf;   // cols  0.. 3
        const float* p2 = (rv && lane != 63) ? (p + 4) : zbuf;   // cols  4.. 7
        const float4 a0 = *(const float4*)p0;
        const float4 a1 = *(const float4*)p1;
        const float4 a2 = *(const float4*)p2;
        dst[0] = a0.x; dst[1] = a0.y; dst[2]  = a0.z; dst[3]  = a0.w;
        dst[4] = a1.x; dst[5] = a1.y; dst[6]  = a1.z; dst[7]  = a1.w;
        dst[8] = a2.x; dst[9] = a2.y; dst[10] = a2.z; dst[11] = a2.w;
    };

    // prime: input rows rg-3 .. rg+3 -> slots 0..6
    #pragma unroll
    for (int r = 0; r < 7; ++r)
        loadrow(win[r], rg - 3 + r);

    // persp pipeline: pvn holds the NEXT output row's perspective
    float4 pvn = *(const float4*)(pp + (size_t)rg * NW + colbase);

    #pragma unroll
    for (int o = 0; o < 16; ++o) {
        // (a) prefetch input row rg+o+4 (used NEXT iteration) — load-use
        //     distance = one full iteration of FMAs, hides HBM latency
        float nxt[12];
        if (o < 15)
            loadrow(nxt, rg + o + 4);

        const float4 pv = pvn;
        if (o < 15)
            pvn = *(const float4*)(pp + (size_t)(rg + o + 1) * NW + colbase);

        // (b) compute output row rg+o from committed slots only
        const float pva[4] = {pv.x, pv.y, pv.z, pv.w};
        float res[4];
        #pragma unroll
        for (int k = 0; k < 4; ++k) {
            const float z  = fmaf(beta, pva[k], gamma);
            const float sg = __builtin_amdgcn_rcpf(1.0f + __expf(-z));
            const float sigma = fmaxf(alpha * sg, 1e-4f);
            const float t  = 0.5f * __builtin_amdgcn_rcpf(sigma * sigma);
            const float g  = __expf(-t);       // tap weight = g^(d^2)
            const float g2 = g * g;
            const float p4 = g2 * g2;          // g^4
            const float p9 = p4 * p4 * g;      // g^9
            const float S  = fmaf(2.0f, (g + p4) + p9, 1.0f);
            const float inv  = __builtin_amdgcn_rcpf(S);
            const float inv2 = inv * inv;      // 1/S^2

            float rs[7];
            #pragma unroll
            for (int j = 0; j < 7; ++j) {
                const int s = (o + j) % 7;     // slot of input row rg+o-3+j
                rs[j] = fmaf(p9, win[s][k+1] + win[s][k+7],
                        fmaf(p4, win[s][k+2] + win[s][k+6],
                        fmaf(g,  win[s][k+3] + win[s][k+5],
                                 win[s][k+4])));
            }
            const float acc = fmaf(p9, rs[0] + rs[6],
                              fmaf(p4, rs[1] + rs[5],
                              fmaf(g,  rs[2] + rs[4],
                                       rs[3])));
            res[k] = acc * inv2;
        }
        *(float4*)(outp + (size_t)(rg + o) * NW + colbase) =
            make_float4(res[0], res[1], res[2], res[3]);

        // (c) commit prefetched row into the now-dead slot (held rg+o-3)
        if (o < 15) {
            const int s = o % 7;
            #pragma unroll
            for (int q = 0; q < 12; ++q)
                win[s][q] = nxt[q];
        }
    }
}

extern "C" void kernel_launch(void* const* d_in, const int* in_sizes, int n_in,
                              void* d_out, int out_size, void* d_ws, size_t ws_size,
                              hipStream_t stream) {
    const float* x     = (const float*)d_in[0];
    const float* persp = (const float*)d_in[1];
    const float* alpha = (const float*)d_in[2];
    const float* beta  = (const float*)d_in[3];
    const float* gamma = (const float*)d_in[4];
    float* outp        = (float*)d_out;
    // kernel_size (d_in[5]) fixed at 7 per the reference setup
    dim3 grid(NC, NH / TH, NB);   // 64 x 4 x 4 = 1024 blocks, 4/CU
    adaptive_gauss7<<<grid, dim3(256), 0, stream>>>(x, persp, alpha, beta, gamma, outp);
}